// Round 3
// baseline (15462.108 us; speedup 1.0000x reference)
//
#include <hip/hip_runtime.h>
#include <hip/hip_bf16.h>

typedef __hip_bfloat16 bf16;

#define BB   32
#define IMG  512
#define PP   16
#define DD   256
#define GG   32
#define NN   1024          // GG*GG
#define DQ_  32
#define DF_  1024
#define DEPTH_ 8

// cumulative fp32-element offsets of the 21 inputs
__device__ __host__ __forceinline__ long long cum(int s) {
    const long long C[22] = {
        0LL, 8388608LL, 8454144LL, 8454400LL, 8716544LL, 8782080LL, 8782336LL,
        8784384LL, 8786432LL, 8851968LL, 8852224LL, 8917760LL, 8918016LL,
        9442304LL, 9444352LL, 9444360LL, 11541512LL, 11549704LL, 13646856LL,
        13648904LL, 13649160LL, 13649161LL};
    return C[s];
}
#define IN_TOTAL 13649161LL

__device__ __forceinline__ float b2f(bf16 v) { return __bfloat162float(v); }
__device__ __forceinline__ float gelu_exact(float x) {
    return 0.5f * x * (1.0f + erff(x * 0.70710678118654752440f));
}

// ---------------- dtype detect (even 16-bit halves of w1) ----------------
__global__ __launch_bounds__(256) void k_detect(const void* w1raw, int* flagp) {
    __shared__ int sh_huge, sh_nz;
    if (threadIdx.x == 0) { sh_huge = 0; sh_nz = 0; }
    __syncthreads();
    const unsigned short* u = (const unsigned short*)w1raw;
    int huge = 0, nz = 0;
    for (int i = threadIdx.x; i < 4096; i += 256) {
        unsigned short h = u[2 * i];
        int e = (h >> 7) & 0xFF;
        if (e >= 137) huge = 1;
        if (h != 0) nz = 1;
    }
    if (huge) atomicOr(&sh_huge, 1);
    if (nz)   atomicOr(&sh_nz, 1);
    __syncthreads();
    if (threadIdx.x == 0) *flagp = (sh_huge || !sh_nz) ? 1 : 0;  // 1 -> f32
}

struct SrcPtrs { const void* p[21]; };

__global__ __launch_bounds__(256) void k_convert(SrcPtrs sp, float* dst,
                                                 const int* flagp) {
    long long i = (long long)blockIdx.x * 256 + threadIdx.x;
    if (i >= IN_TOTAL) return;
    const int flag = *flagp;
    int seg = 0;
    #pragma unroll
    for (int s = 1; s <= 20; ++s) seg += (i >= cum(s)) ? 1 : 0;
    long long base = 0;
    const void* p = sp.p[0];
    #pragma unroll
    for (int s = 1; s <= 20; ++s)
        if (seg == s) { base = cum(s); p = sp.p[s]; }
    long long off = i - base;
    dst[i] = flag ? ((const float*)p)[off] : b2f(((const bf16*)p)[off]);
}

// ---------------- patch embed ----------------
__global__ __launch_bounds__(256) void k_patch(
    const float* __restrict__ x, const float* __restrict__ wp,
    const float* __restrict__ bp, const float* __restrict__ pos,
    float* __restrict__ h) {
    __shared__ float px[4][256];
    const int base = blockIdx.x * 4;
    const int tid  = threadIdx.x;
    const int pi = tid >> 4, pj = tid & 15;
    for (int t = 0; t < 4; ++t) {
        int tok = base + t;
        int b  = tok >> 10;
        int n  = tok & (NN - 1);
        int gi = n >> 5, gj = n & 31;
        px[t][tid] = x[(size_t)(b * IMG + gi * PP + pi) * IMG + gj * PP + pj];
    }
    __syncthreads();
    const int d = tid;
    float a0 = 0.f, a1 = 0.f, a2 = 0.f, a3 = 0.f;
    const float* wrow = wp + (size_t)d * 256;
    for (int k = 0; k < 256; ++k) {
        float w = wrow[k];
        a0 += px[0][k] * w; a1 += px[1][k] * w;
        a2 += px[2][k] * w; a3 += px[3][k] * w;
    }
    float bias = bp[d];
    float acc[4] = {a0, a1, a2, a3};
    for (int t = 0; t < 4; ++t) {
        int tok = base + t;
        int n = tok & (NN - 1);
        h[(size_t)tok * DD + d] = acc[t] + bias + pos[(size_t)n * DD + d];
    }
}

// ---------------- depthwise Laplacian (SAME, zero pad) ----------------
__global__ __launch_bounds__(256) void k_lap(const float* __restrict__ h,
                                             float* __restrict__ e) {
    int idx = blockIdx.x * 256 + threadIdx.x;
    int n  = (idx >> 8) & (NN - 1);
    int gi = n >> 5, gj = n & 31;
    float c  = h[idx];
    float up = (gi > 0)  ? h[idx - GG * DD] : 0.f;
    float dn = (gi < 31) ? h[idx + GG * DD] : 0.f;
    float lf = (gj > 0)  ? h[idx - DD] : 0.f;
    float rt = (gj < 31) ? h[idx + DD] : 0.f;
    e[idx] = 4.f * c - up - dn - lf - rt;
}

// ---------------- edge linear: h += tanh(e @ w_edge + b_edge) ----------------
__global__ __launch_bounds__(256) void k_edge_lin(
    const float* __restrict__ e, const float* __restrict__ we,
    const float* __restrict__ be, float* __restrict__ h) {
    __shared__ float es[4][256];
    const int base = blockIdx.x * 4;
    const int tid  = threadIdx.x;
    for (int t = 0; t < 4; ++t) es[t][tid] = e[(size_t)(base + t) * DD + tid];
    __syncthreads();
    float a0 = 0.f, a1 = 0.f, a2 = 0.f, a3 = 0.f;
    for (int k = 0; k < 256; ++k) {
        float w = we[(size_t)k * DD + tid];
        a0 += es[0][k] * w; a1 += es[1][k] * w;
        a2 += es[2][k] * w; a3 += es[3][k] * w;
    }
    float bias = be[tid];
    h[(size_t)(base + 0) * DD + tid] += tanhf(a0 + bias);
    h[(size_t)(base + 1) * DD + tid] += tanhf(a1 + bias);
    h[(size_t)(base + 2) * DD + tid] += tanhf(a2 + bias);
    h[(size_t)(base + 3) * DD + tid] += tanhf(a3 + bias);
}

// ---------------- LayerNorm ----------------
__global__ __launch_bounds__(256) void k_ln(
    const float* __restrict__ h, const float* __restrict__ g,
    const float* __restrict__ b, float* __restrict__ xn, int layer) {
    const int row = blockIdx.x, tid = threadIdx.x;
    __shared__ float red[4];
    float x = h[(size_t)row * DD + tid];
    float s = x;
    #pragma unroll
    for (int o = 32; o; o >>= 1) s += __shfl_down(s, o, 64);
    if ((tid & 63) == 0) red[tid >> 6] = s;
    __syncthreads();
    float m = (red[0] + red[1] + red[2] + red[3]) * (1.f / 256.f);
    __syncthreads();
    float t = x - m;
    float s2 = t * t;
    #pragma unroll
    for (int o = 32; o; o >>= 1) s2 += __shfl_down(s2, o, 64);
    if ((tid & 63) == 0) red[tid >> 6] = s2;
    __syncthreads();
    float var = (red[0] + red[1] + red[2] + red[3]) * (1.f / 256.f);
    float r = rsqrtf(var + 1e-5f);
    xn[(size_t)row * DD + tid] =
        t * r * g[layer * DD + tid] + b[layer * DD + tid];
}

// ---------------- q,k projections ----------------
__global__ __launch_bounds__(256) void k_qk(
    const float* __restrict__ xn, const float* __restrict__ wq,
    const float* __restrict__ bq, const float* __restrict__ wk,
    const float* __restrict__ bk, float* __restrict__ q,
    float* __restrict__ kk, int layer) {
    __shared__ float xs[4][256];
    const int base = blockIdx.x * 4;
    const int tid  = threadIdx.x;
    for (int t = 0; t < 4; ++t) xs[t][tid] = xn[(size_t)(base + t) * DD + tid];
    __syncthreads();
    const int t = tid >> 6;
    const int which = (tid >> 5) & 1;
    const int j = tid & 31;
    const float* w  = (which ? wk : wq) + (size_t)layer * DD * DQ_;
    const float* bi = (which ? bk : bq) + (size_t)layer * DQ_;
    float acc = bi[j];
    for (int k = 0; k < 256; ++k) acc += xs[t][k] * w[(size_t)k * DQ_ + j];
    float* out = which ? kk : q;
    out[(size_t)(base + t) * DQ_ + j] = acc;
}

// ---------------- v projection ----------------
__global__ __launch_bounds__(256) void k_v(
    const float* __restrict__ xn, const float* __restrict__ wv,
    const float* __restrict__ bv, float* __restrict__ v, int layer) {
    __shared__ float xs[4][256];
    const int base = blockIdx.x * 4;
    const int tid  = threadIdx.x;
    for (int t = 0; t < 4; ++t) xs[t][tid] = xn[(size_t)(base + t) * DD + tid];
    __syncthreads();
    const float* w = wv + (size_t)layer * DD * DD;
    float a0 = 0.f, a1 = 0.f, a2 = 0.f, a3 = 0.f;
    for (int k = 0; k < 256; ++k) {
        float ww = w[(size_t)k * DD + tid];
        a0 += xs[0][k] * ww; a1 += xs[1][k] * ww;
        a2 += xs[2][k] * ww; a3 += xs[3][k] * ww;
    }
    float bias = bv[layer * DD + tid];
    v[(size_t)(base + 0) * DD + tid] = a0 + bias;
    v[(size_t)(base + 1) * DD + tid] = a1 + bias;
    v[(size_t)(base + 2) * DD + tid] = a2 + bias;
    v[(size_t)(base + 3) * DD + tid] = a3 + bias;
}

// ---------------- criss-cross attention + residual ----------------
__global__ __launch_bounds__(256) void k_attn(
    const float* __restrict__ q, const float* __restrict__ kk,
    const float* __restrict__ v, const float* __restrict__ xn,
    float* __restrict__ h, const float* __restrict__ gamma, int layer) {
    const int blk = blockIdx.x;            // b*1024 + gi*32 + gj
    const int b  = blk >> 10;
    const int gi = (blk >> 5) & 31;
    const int gj = blk & 31;
    const int tid = threadIdx.x;
    __shared__ float qs[32];
    __shared__ float as[64];
    if (tid < 32) qs[tid] = q[(size_t)blk * DQ_ + tid];
    __syncthreads();
    if (tid < 64) {
        int kidx;
        if (tid < 32) kidx = (b * GG + gi) * GG + tid;        // row
        else          kidx = (b * GG + (tid - 32)) * GG + gj; // col
        const float* kr = kk + (size_t)kidx * DQ_;
        float s = 0.f;
        #pragma unroll
        for (int c = 0; c < 32; ++c) s += qs[c] * kr[c];
        s *= 0.17677669529663687f;
        if (tid >= 32 && (tid - 32) == gi) s -= 1e9f;
        float m = s;
        #pragma unroll
        for (int o = 32; o; o >>= 1) m = fmaxf(m, __shfl_xor(m, o, 64));
        float e = expf(s - m);
        float sum = e;
        #pragma unroll
        for (int o = 32; o; o >>= 1) sum += __shfl_xor(sum, o, 64);
        as[tid] = e / sum;
    }
    __syncthreads();
    const int d = tid;
    float out = 0.f;
    const float* vrow = v + ((size_t)(b * GG + gi) * GG) * DD + d;
    #pragma unroll 4
    for (int w = 0; w < 32; ++w) out += as[w] * vrow[(size_t)w * DD];
    const float* vcol = v + ((size_t)b * NN + gj) * DD + d;
    #pragma unroll 4
    for (int u = 0; u < 32; ++u) out += as[32 + u] * vcol[(size_t)u * GG * DD];
    size_t idx = (size_t)blk * DD + d;
    h[idx] += xn[idx] + gamma[layer] * out;
}

// ---------------- fused MLP ----------------
__global__ __launch_bounds__(1024) void k_mlp(
    const float* __restrict__ xn, const float* __restrict__ w1,
    const float* __restrict__ b1, const float* __restrict__ w2,
    const float* __restrict__ b2, float* __restrict__ h, int layer) {
    __shared__ float xs[4][256];
    __shared__ float hs[4][1024];
    const int base = blockIdx.x * 4;
    const int tid  = threadIdx.x;
    xs[tid >> 8][tid & 255] = xn[(size_t)(base + (tid >> 8)) * DD + (tid & 255)];
    __syncthreads();
    {
        const float* W1 = w1 + (size_t)layer * DD * DF_;
        float bias = b1[layer * DF_ + tid];
        float a0 = bias, a1 = bias, a2 = bias, a3 = bias;
        for (int k = 0; k < 256; ++k) {
            float w = W1[(size_t)k * DF_ + tid];
            a0 += xs[0][k] * w; a1 += xs[1][k] * w;
            a2 += xs[2][k] * w; a3 += xs[3][k] * w;
        }
        hs[0][tid] = gelu_exact(a0); hs[1][tid] = gelu_exact(a1);
        hs[2][tid] = gelu_exact(a2); hs[3][tid] = gelu_exact(a3);
    }
    __syncthreads();
    {
        const int tq = tid >> 8, d = tid & 255;
        const float* W2 = w2 + (size_t)layer * DF_ * DD;
        float acc = b2[layer * DD + d];
        for (int k = 0; k < 1024; ++k) acc += hs[tq][k] * W2[(size_t)k * DD + d];
        h[(size_t)(base + tq) * DD + d] += acc;
    }
}

// ---------------- head: out = h . w_head + b_head (f32 out) ----------------
__global__ __launch_bounds__(256) void k_head(
    const float* __restrict__ h, const float* __restrict__ wh,
    const float* __restrict__ bh, float* __restrict__ out) {
    const int tok  = blockIdx.x * 4 + (threadIdx.x >> 6);
    const int lane = threadIdx.x & 63;
    float acc = 0.f;
    #pragma unroll
    for (int i = 0; i < 4; ++i)
        acc += h[(size_t)tok * DD + lane + 64 * i] * wh[lane + 64 * i];
    #pragma unroll
    for (int o = 32; o; o >>= 1) acc += __shfl_down(acc, o, 64);
    if (lane == 0) out[tok] = acc + bh[0];
}

extern "C" void kernel_launch(void* const* d_in, const int* in_sizes, int n_in,
                              void* d_out, int out_size, void* d_ws, size_t ws_size,
                              hipStream_t stream) {
    float* out = (float*)d_out;
    float* ws = (float*)d_ws;

    const size_t BIG = (size_t)BB * NN * DD;                  // 8,388,608
    const size_t bufs = 3 * BIG + 2 * (size_t)BB * NN * DQ_;  // 27,262,976 floats
    const size_t need_convert = ((size_t)16 + 13649168 + bufs) * 4;

    const float *fx, *fwp, *fbp, *fpos, *fwe, *fbe, *flg, *flb, *fwq, *fbq,
                *fwk, *fbk, *fwv, *fbv, *fgam, *fw1, *fb1, *fw2, *fb2, *fwh, *fbh;
    float* big;

    const bool do_convert = (ws_size >= need_convert);
    if (do_convert) {
        int* flagp = (int*)d_ws;
        float* f = ws + 16;
        SrcPtrs sp;
        for (int i = 0; i < 21; ++i) sp.p[i] = d_in[i];
        k_detect<<<1, 256, 0, stream>>>(d_in[15], flagp);
        k_convert<<<(int)((IN_TOTAL + 255) / 256), 256, 0, stream>>>(sp, f, flagp);
        fx  = f + cum(0);  fwp = f + cum(1);  fbp = f + cum(2);  fpos = f + cum(3);
        fwe = f + cum(4);  fbe = f + cum(5);  flg = f + cum(6);  flb  = f + cum(7);
        fwq = f + cum(8);  fbq = f + cum(9);  fwk = f + cum(10); fbk  = f + cum(11);
        fwv = f + cum(12); fbv = f + cum(13); fgam = f + cum(14);
        fw1 = f + cum(15); fb1 = f + cum(16); fw2 = f + cum(17); fb2 = f + cum(18);
        fwh = f + cum(19); fbh = f + cum(20);
        big = f + 13649168;
    } else {
        // direct f32 reads (inputs proven float32)
        fx  = (const float*)d_in[0];  fwp = (const float*)d_in[1];
        fbp = (const float*)d_in[2];  fpos = (const float*)d_in[3];
        fwe = (const float*)d_in[4];  fbe = (const float*)d_in[5];
        flg = (const float*)d_in[6];  flb = (const float*)d_in[7];
        fwq = (const float*)d_in[8];  fbq = (const float*)d_in[9];
        fwk = (const float*)d_in[10]; fbk = (const float*)d_in[11];
        fwv = (const float*)d_in[12]; fbv = (const float*)d_in[13];
        fgam = (const float*)d_in[14];
        fw1 = (const float*)d_in[15]; fb1 = (const float*)d_in[16];
        fw2 = (const float*)d_in[17]; fb2 = (const float*)d_in[18];
        fwh = (const float*)d_in[19]; fbh = (const float*)d_in[20];
        big = ws + 16;
    }

    float* h   = big;
    float* xn  = h  + BIG;
    float* q   = xn + BIG;
    float* kk  = q  + (size_t)BB * NN * DQ_;
    float* v   = kk + (size_t)BB * NN * DQ_;

    const int TOK = BB * NN;               // 32768

    k_patch<<<TOK / 4, 256, 0, stream>>>(fx, fwp, fbp, fpos, h);
    k_lap<<<TOK, 256, 0, stream>>>(h, xn);
    k_edge_lin<<<TOK / 4, 256, 0, stream>>>(xn, fwe, fbe, h);

    for (int l = 0; l < DEPTH_; ++l) {
        k_ln<<<TOK, 256, 0, stream>>>(h, flg, flb, xn, l);
        k_qk<<<TOK / 4, 256, 0, stream>>>(xn, fwq, fbq, fwk, fbk, q, kk, l);
        k_v<<<TOK / 4, 256, 0, stream>>>(xn, fwv, fbv, v, l);
        k_attn<<<TOK, 256, 0, stream>>>(q, kk, v, xn, h, fgam, l);
        k_ln<<<TOK, 256, 0, stream>>>(h, flg, flb, xn, l);
        k_mlp<<<TOK / 4, 1024, 0, stream>>>(xn, fw1, fb1, fw2, fb2, h, l);
    }

    k_head<<<TOK / 4, 256, 0, stream>>>(h, fwh, fbh, out);
}

// Round 4
// 4007.031 us; speedup vs baseline: 3.8587x; 3.8587x over previous
//
#include <hip/hip_runtime.h>
#include <hip/hip_bf16.h>

#define BB   32
#define IMG  512
#define PP   16
#define DD   256
#define GG   32
#define NN   1024
#define DQ_  32
#define DF_  1024
#define DEPTH_ 8

using short8  = __attribute__((ext_vector_type(8))) short;
using floatx4 = __attribute__((ext_vector_type(4))) float;

__device__ __forceinline__ float bu2f(unsigned short u) {
    return __uint_as_float(((unsigned int)u) << 16);
}
__device__ __forceinline__ unsigned short f2b(float f) {   // round-to-nearest-even
    unsigned int u = __float_as_uint(f);
    u += 0x7fffu + ((u >> 16) & 1u);
    return (unsigned short)(u >> 16);
}
__device__ __forceinline__ float gelu_exact(float x) {
    return 0.5f * x * (1.0f + erff(x * 0.70710678118654752440f));
}

// ---------------- weight transpose+convert: [L][R][C] f32 -> [L][C][R] bf16 ----------------
__global__ __launch_bounds__(256) void k_wtrans(const float* __restrict__ in,
                                                unsigned short* __restrict__ out,
                                                int R, int C) {
    __shared__ float tile[32][33];
    const int l = blockIdx.z;
    const int r0 = blockIdx.x * 32, c0 = blockIdx.y * 32;
    const int tx = threadIdx.x & 31, ty = threadIdx.x >> 5;   // 8 rows of 32
    const float* src = in + (size_t)l * R * C;
    unsigned short* dst = out + (size_t)l * R * C;
    #pragma unroll
    for (int i = 0; i < 4; ++i)
        tile[ty + i * 8][tx] = src[(size_t)(r0 + ty + i * 8) * C + c0 + tx];
    __syncthreads();
    #pragma unroll
    for (int i = 0; i < 4; ++i)
        dst[(size_t)(c0 + ty + i * 8) * R + r0 + tx] = f2b(tile[tx][ty + i * 8]);
}

// ---------------- MFMA bf16 GEMM: C[M,N] = A[M,K] @ Bt[N,K]^T ----------------
// 64x64 tile, 256 threads (4 waves 2x2). MODE 0: Cb = bf16(gelu(acc+bias))
// MODE 1: Cf += acc + bias
template <int K, int N, int MODE>
__global__ __launch_bounds__(256) void k_gemm(
    const unsigned short* __restrict__ A, const unsigned short* __restrict__ Bt,
    const float* __restrict__ bias, unsigned short* __restrict__ Cb,
    float* __restrict__ Cf) {
    __shared__ alignas(16) unsigned short As[64 * 32];
    __shared__ alignas(16) unsigned short Bs[64 * 32];
    const int t  = threadIdx.x;
    const int m0 = blockIdx.x * 64, n0 = blockIdx.y * 64;
    const int row = t >> 2, ch = t & 3;
    const unsigned short* ga = A  + (size_t)(m0 + row) * K + ch * 8;
    const unsigned short* gb = Bt + (size_t)(n0 + row) * K + ch * 8;

    const int lane = t & 63, wid = t >> 6;
    const int quad = lane >> 4, r = lane & 15;
    const int wm = (wid >> 1) * 32, wn = (wid & 1) * 32;

    floatx4 acc00 = {0.f, 0.f, 0.f, 0.f}, acc01 = {0.f, 0.f, 0.f, 0.f};
    floatx4 acc10 = {0.f, 0.f, 0.f, 0.f}, acc11 = {0.f, 0.f, 0.f, 0.f};

    uint4 ra = *(const uint4*)ga;
    uint4 rb = *(const uint4*)gb;
    const int KS = K / 32;
    for (int ks = 0; ks < KS; ++ks) {
        __syncthreads();
        *(uint4*)&As[t * 8] = ra;
        *(uint4*)&Bs[t * 8] = rb;
        __syncthreads();
        if (ks + 1 < KS) {
            ra = *(const uint4*)(ga + (ks + 1) * 32);
            rb = *(const uint4*)(gb + (ks + 1) * 32);
        }
        short8 a0 = *(const short8*)&As[(wm + r) * 32 + quad * 8];
        short8 a1 = *(const short8*)&As[(wm + 16 + r) * 32 + quad * 8];
        short8 b0 = *(const short8*)&Bs[(wn + r) * 32 + quad * 8];
        short8 b1 = *(const short8*)&Bs[(wn + 16 + r) * 32 + quad * 8];
        acc00 = __builtin_amdgcn_mfma_f32_16x16x32_bf16(a0, b0, acc00, 0, 0, 0);
        acc01 = __builtin_amdgcn_mfma_f32_16x16x32_bf16(a0, b1, acc01, 0, 0, 0);
        acc10 = __builtin_amdgcn_mfma_f32_16x16x32_bf16(a1, b0, acc10, 0, 0, 0);
        acc11 = __builtin_amdgcn_mfma_f32_16x16x32_bf16(a1, b1, acc11, 0, 0, 0);
    }
    const int nA = n0 + wn + r;
    const int nB = nA + 16;
    const float bias0 = bias[nA], bias1 = bias[nB];
    #pragma unroll
    for (int i = 0; i < 2; ++i) {
        floatx4 aj0 = i ? acc10 : acc00;
        floatx4 aj1 = i ? acc11 : acc01;
        const int mb = m0 + wm + i * 16 + quad * 4;
        #pragma unroll
        for (int g = 0; g < 4; ++g) {
            const int m = mb + g;
            if (MODE == 0) {
                Cb[(size_t)m * N + nA] = f2b(gelu_exact(aj0[g] + bias0));
                Cb[(size_t)m * N + nB] = f2b(gelu_exact(aj1[g] + bias1));
            } else {
                Cf[(size_t)m * N + nA] += aj0[g] + bias0;
                Cf[(size_t)m * N + nB] += aj1[g] + bias1;
            }
        }
    }
}

// ---------------- patch embed ----------------
__global__ __launch_bounds__(256) void k_patch(
    const float* __restrict__ x, const float* __restrict__ wp,
    const float* __restrict__ bp, const float* __restrict__ pos,
    float* __restrict__ h) {
    __shared__ float px[4][256];
    const int base = blockIdx.x * 4;
    const int tid  = threadIdx.x;
    const int pi = tid >> 4, pj = tid & 15;
    for (int t = 0; t < 4; ++t) {
        int tok = base + t;
        int b  = tok >> 10;
        int n  = tok & (NN - 1);
        int gi = n >> 5, gj = n & 31;
        px[t][tid] = x[(size_t)(b * IMG + gi * PP + pi) * IMG + gj * PP + pj];
    }
    __syncthreads();
    const int d = tid;
    float a0 = 0.f, a1 = 0.f, a2 = 0.f, a3 = 0.f;
    const float* wrow = wp + (size_t)d * 256;
    for (int k = 0; k < 256; ++k) {
        float w = wrow[k];
        a0 += px[0][k] * w; a1 += px[1][k] * w;
        a2 += px[2][k] * w; a3 += px[3][k] * w;
    }
    float bias = bp[d];
    float acc[4] = {a0, a1, a2, a3};
    for (int t = 0; t < 4; ++t) {
        int tok = base + t;
        int n = tok & (NN - 1);
        h[(size_t)tok * DD + d] = acc[t] + bias + pos[(size_t)n * DD + d];
    }
}

// ---------------- depthwise Laplacian (SAME, zero pad) ----------------
__global__ __launch_bounds__(256) void k_lap(const float* __restrict__ h,
                                             float* __restrict__ e) {
    int idx = blockIdx.x * 256 + threadIdx.x;
    int n  = (idx >> 8) & (NN - 1);
    int gi = n >> 5, gj = n & 31;
    float c  = h[idx];
    float up = (gi > 0)  ? h[idx - GG * DD] : 0.f;
    float dn = (gi < 31) ? h[idx + GG * DD] : 0.f;
    float lf = (gj > 0)  ? h[idx - DD] : 0.f;
    float rt = (gj < 31) ? h[idx + DD] : 0.f;
    e[idx] = 4.f * c - up - dn - lf - rt;
}

// ---------------- edge linear: h += tanh(e @ w_edge + b_edge) ----------------
__global__ __launch_bounds__(256) void k_edge_lin(
    const float* __restrict__ e, const float* __restrict__ we,
    const float* __restrict__ be, float* __restrict__ h) {
    __shared__ float es[4][256];
    const int base = blockIdx.x * 4;
    const int tid  = threadIdx.x;
    for (int t = 0; t < 4; ++t) es[t][tid] = e[(size_t)(base + t) * DD + tid];
    __syncthreads();
    float a0 = 0.f, a1 = 0.f, a2 = 0.f, a3 = 0.f;
    for (int k = 0; k < 256; ++k) {
        float w = we[(size_t)k * DD + tid];
        a0 += es[0][k] * w; a1 += es[1][k] * w;
        a2 += es[2][k] * w; a3 += es[3][k] * w;
    }
    float bias = be[tid];
    h[(size_t)(base + 0) * DD + tid] += tanhf(a0 + bias);
    h[(size_t)(base + 1) * DD + tid] += tanhf(a1 + bias);
    h[(size_t)(base + 2) * DD + tid] += tanhf(a2 + bias);
    h[(size_t)(base + 3) * DD + tid] += tanhf(a3 + bias);
}

// ---------------- LayerNorm -> bf16 xn ----------------
__global__ __launch_bounds__(256) void k_ln(
    const float* __restrict__ h, const float* __restrict__ g,
    const float* __restrict__ b, unsigned short* __restrict__ xnb, int layer) {
    const int row = blockIdx.x, tid = threadIdx.x;
    __shared__ float red[4];
    float x = h[(size_t)row * DD + tid];
    float s = x;
    #pragma unroll
    for (int o = 32; o; o >>= 1) s += __shfl_down(s, o, 64);
    if ((tid & 63) == 0) red[tid >> 6] = s;
    __syncthreads();
    float m = (red[0] + red[1] + red[2] + red[3]) * (1.f / 256.f);
    __syncthreads();
    float t = x - m;
    float s2 = t * t;
    #pragma unroll
    for (int o = 32; o; o >>= 1) s2 += __shfl_down(s2, o, 64);
    if ((tid & 63) == 0) red[tid >> 6] = s2;
    __syncthreads();
    float var = (red[0] + red[1] + red[2] + red[3]) * (1.f / 256.f);
    float r = rsqrtf(var + 1e-5f);
    xnb[(size_t)row * DD + tid] =
        f2b(t * r * g[layer * DD + tid] + b[layer * DD + tid]);
}

// ---------------- q,k projections (reads bf16 xn) ----------------
__global__ __launch_bounds__(256) void k_qk(
    const unsigned short* __restrict__ xnb, const float* __restrict__ wq,
    const float* __restrict__ bq, const float* __restrict__ wk,
    const float* __restrict__ bk, float* __restrict__ q,
    float* __restrict__ kk, int layer) {
    __shared__ float xs[4][256];
    const int base = blockIdx.x * 4;
    const int tid  = threadIdx.x;
    for (int t = 0; t < 4; ++t)
        xs[t][tid] = bu2f(xnb[(size_t)(base + t) * DD + tid]);
    __syncthreads();
    const int t = tid >> 6;
    const int which = (tid >> 5) & 1;
    const int j = tid & 31;
    const float* w  = (which ? wk : wq) + (size_t)layer * DD * DQ_;
    const float* bi = (which ? bk : bq) + (size_t)layer * DQ_;
    float acc = bi[j];
    for (int k = 0; k < 256; ++k) acc += xs[t][k] * w[(size_t)k * DQ_ + j];
    float* out = which ? kk : q;
    out[(size_t)(base + t) * DQ_ + j] = acc;
}

// ---------------- v projection (bf16 out) ----------------
__global__ __launch_bounds__(256) void k_v(
    const unsigned short* __restrict__ xnb, const float* __restrict__ wv,
    const float* __restrict__ bv, unsigned short* __restrict__ v, int layer) {
    __shared__ float xs[4][256];
    const int base = blockIdx.x * 4;
    const int tid  = threadIdx.x;
    for (int t = 0; t < 4; ++t)
        xs[t][tid] = bu2f(xnb[(size_t)(base + t) * DD + tid]);
    __syncthreads();
    const float* w = wv + (size_t)layer * DD * DD;
    float a0 = 0.f, a1 = 0.f, a2 = 0.f, a3 = 0.f;
    for (int k = 0; k < 256; ++k) {
        float ww = w[(size_t)k * DD + tid];
        a0 += xs[0][k] * ww; a1 += xs[1][k] * ww;
        a2 += xs[2][k] * ww; a3 += xs[3][k] * ww;
    }
    float bias = bv[layer * DD + tid];
    v[(size_t)(base + 0) * DD + tid] = f2b(a0 + bias);
    v[(size_t)(base + 1) * DD + tid] = f2b(a1 + bias);
    v[(size_t)(base + 2) * DD + tid] = f2b(a2 + bias);
    v[(size_t)(base + 3) * DD + tid] = f2b(a3 + bias);
}

// ---------------- criss-cross attention + residual ----------------
__global__ __launch_bounds__(256) void k_attn(
    const float* __restrict__ q, const float* __restrict__ kk,
    const unsigned short* __restrict__ v, const unsigned short* __restrict__ xnb,
    float* __restrict__ h, const float* __restrict__ gamma, int layer) {
    const int blk = blockIdx.x;            // b*1024 + gi*32 + gj
    const int b  = blk >> 10;
    const int gi = (blk >> 5) & 31;
    const int gj = blk & 31;
    const int tid = threadIdx.x;
    __shared__ float qs[32];
    __shared__ float as[64];
    if (tid < 32) qs[tid] = q[(size_t)blk * DQ_ + tid];
    __syncthreads();
    if (tid < 64) {
        int kidx;
        if (tid < 32) kidx = (b * GG + gi) * GG + tid;        // row
        else          kidx = (b * GG + (tid - 32)) * GG + gj; // col
        const float* kr = kk + (size_t)kidx * DQ_;
        float s = 0.f;
        #pragma unroll
        for (int c = 0; c < 32; ++c) s += qs[c] * kr[c];
        s *= 0.17677669529663687f;
        if (tid >= 32 && (tid - 32) == gi) s -= 1e9f;
        float m = s;
        #pragma unroll
        for (int o = 32; o; o >>= 1) m = fmaxf(m, __shfl_xor(m, o, 64));
        float e = expf(s - m);
        float sum = e;
        #pragma unroll
        for (int o = 32; o; o >>= 1) sum += __shfl_xor(sum, o, 64);
        as[tid] = e / sum;
    }
    __syncthreads();
    const int d = tid;
    float out = 0.f;
    const unsigned short* vrow = v + ((size_t)(b * GG + gi) * GG) * DD + d;
    #pragma unroll 4
    for (int w = 0; w < 32; ++w) out += as[w] * bu2f(vrow[(size_t)w * DD]);
    const unsigned short* vcol = v + ((size_t)b * NN + gj) * DD + d;
    #pragma unroll 4
    for (int u = 0; u < 32; ++u) out += as[32 + u] * bu2f(vcol[(size_t)u * GG * DD]);
    size_t idx = (size_t)blk * DD + d;
    h[idx] += bu2f(xnb[idx]) + gamma[layer] * out;
}

// ---------------- head ----------------
__global__ __launch_bounds__(256) void k_head(
    const float* __restrict__ h, const float* __restrict__ wh,
    const float* __restrict__ bh, float* __restrict__ out) {
    const int tok  = blockIdx.x * 4 + (threadIdx.x >> 6);
    const int lane = threadIdx.x & 63;
    float acc = 0.f;
    #pragma unroll
    for (int i = 0; i < 4; ++i)
        acc += h[(size_t)tok * DD + lane + 64 * i] * wh[lane + 64 * i];
    #pragma unroll
    for (int o = 32; o; o >>= 1) acc += __shfl_down(acc, o, 64);
    if (lane == 0) out[tok] = acc + bh[0];
}

extern "C" void kernel_launch(void* const* d_in, const int* in_sizes, int n_in,
                              void* d_out, int out_size, void* d_ws, size_t ws_size,
                              hipStream_t stream) {
    const float* fx   = (const float*)d_in[0];
    const float* fwp  = (const float*)d_in[1];
    const float* fbp  = (const float*)d_in[2];
    const float* fpos = (const float*)d_in[3];
    const float* fwe  = (const float*)d_in[4];
    const float* fbe  = (const float*)d_in[5];
    const float* flg  = (const float*)d_in[6];
    const float* flb  = (const float*)d_in[7];
    const float* fwq  = (const float*)d_in[8];
    const float* fbq  = (const float*)d_in[9];
    const float* fwk  = (const float*)d_in[10];
    const float* fbk  = (const float*)d_in[11];
    const float* fwv  = (const float*)d_in[12];
    const float* fbv  = (const float*)d_in[13];
    const float* fgam = (const float*)d_in[14];
    const float* fw1  = (const float*)d_in[15];
    const float* fb1  = (const float*)d_in[16];
    const float* fw2  = (const float*)d_in[17];
    const float* fb2  = (const float*)d_in[18];
    const float* fwh  = (const float*)d_in[19];
    const float* fbh  = (const float*)d_in[20];
    float* out = (float*)d_out;

    // workspace layout (float offsets); total 23,068,672 floats = 92.3 MB
    float* ws = (float*)d_ws;
    float*          h   = ws;                                   // 8,388,608 f
    unsigned short* xnb = (unsigned short*)(ws + 8388608);      // 8,388,608 bf16
    unsigned short* w1t = (unsigned short*)(ws + 12582912);     // 8*1024*256 bf16
    unsigned short* w2t = (unsigned short*)(ws + 13631488);     // 8*256*1024 bf16
    // scratch region (phase-disjoint aliases):
    float*          q   = ws + 14680064;                        // 1,048,576 f
    float*          kk  = ws + 15728640;                        // 1,048,576 f
    unsigned short* v   = (unsigned short*)(ws + 16777216);     // 8,388,608 bf16
    float*          e   = ws + 14680064;                        // 8,388,608 f (pre-loop only)
    unsigned short* Hc  = (unsigned short*)(ws + 14680064);     // 8192*1024 bf16 (MLP phase)

    const int TOK = BB * NN;               // 32768

    // one-time weight transpose + bf16 convert
    k_wtrans<<<dim3(8, 32, 8),  256, 0, stream>>>(fw1, w1t, 256, 1024);
    k_wtrans<<<dim3(32, 8, 8),  256, 0, stream>>>(fw2, w2t, 1024, 256);

    k_patch<<<TOK / 4, 256, 0, stream>>>(fx, fwp, fbp, fpos, h);
    k_lap<<<TOK, 256, 0, stream>>>(h, e);
    k_edge_lin<<<TOK / 4, 256, 0, stream>>>(e, fwe, fbe, h);

    for (int l = 0; l < DEPTH_; ++l) {
        k_ln<<<TOK, 256, 0, stream>>>(h, flg, flb, xnb, l);
        k_qk<<<TOK / 4, 256, 0, stream>>>(xnb, fwq, fbq, fwk, fbk, q, kk, l);
        k_v<<<TOK / 4, 256, 0, stream>>>(xnb, fwv, fbv, v, l);
        k_attn<<<TOK, 256, 0, stream>>>(q, kk, v, xnb, h, fgam, l);
        k_ln<<<TOK, 256, 0, stream>>>(h, flg, flb, xnb, l);
        for (int c = 0; c < 4; ++c) {
            k_gemm<256, 1024, 0><<<dim3(128, 16), 256, 0, stream>>>(
                xnb + (size_t)c * 8192 * 256, w1t + (size_t)l * 262144,
                fb1 + (size_t)l * 1024, Hc, nullptr);
            k_gemm<1024, 256, 1><<<dim3(128, 4), 256, 0, stream>>>(
                Hc, w2t + (size_t)l * 262144,
                fb2 + (size_t)l * 256, nullptr, h + (size_t)c * 8192 * 256);
        }
    }

    k_head<<<TOK / 4, 256, 0, stream>>>(h, fwh, fbh, out);
}

// Round 5
// 2415.702 us; speedup vs baseline: 6.4007x; 1.6587x over previous
//
#include <hip/hip_runtime.h>
#include <hip/hip_bf16.h>

#define BB   32
#define IMG  512
#define PP   16
#define DD   256
#define GG   32
#define NN   1024
#define DQ_  32
#define DF_  1024
#define DEPTH_ 8

using short8  = __attribute__((ext_vector_type(8))) short;
using floatx4 = __attribute__((ext_vector_type(4))) float;
typedef unsigned short ushort_t;

__device__ __forceinline__ float bu2f(unsigned short u) {
    return __uint_as_float(((unsigned int)u) << 16);
}
__device__ __forceinline__ unsigned short f2b(float f) {   // round-to-nearest-even
    unsigned int u = __float_as_uint(f);
    u += 0x7fffu + ((u >> 16) & 1u);
    return (unsigned short)(u >> 16);
}
__device__ __forceinline__ float gelu_exact(float x) {
    return 0.5f * x * (1.0f + erff(x * 0.70710678118654752440f));
}

// ---------------- weight transpose+convert: [L][R][C] f32 -> [L][C][R] bf16 ----------------
__global__ __launch_bounds__(256) void k_wtrans(const float* __restrict__ in,
                                                unsigned short* __restrict__ out,
                                                int R, int C) {
    __shared__ float tile[32][33];
    const int l = blockIdx.z;
    const int r0 = blockIdx.x * 32, c0 = blockIdx.y * 32;
    const int tx = threadIdx.x & 31, ty = threadIdx.x >> 5;
    const float* src = in + (size_t)l * R * C;
    unsigned short* dst = out + (size_t)l * R * C;
    #pragma unroll
    for (int i = 0; i < 4; ++i)
        tile[ty + i * 8][tx] = src[(size_t)(r0 + ty + i * 8) * C + c0 + tx];
    __syncthreads();
    #pragma unroll
    for (int i = 0; i < 4; ++i)
        dst[(size_t)(c0 + ty + i * 8) * R + r0 + tx] = f2b(tile[tx][ty + i * 8]);
}

// stacked qk transpose: wqkT[l][j][k] = j<32 ? wq[l][k][j] : wk[l][k][j-32]
__global__ __launch_bounds__(256) void k_qktrans(const float* __restrict__ wq,
                                                 const float* __restrict__ wk,
                                                 unsigned short* __restrict__ o) {
    const int l = blockIdx.z, j = blockIdx.x, k = threadIdx.x;
    float v = (j < 32) ? wq[(size_t)l * 8192 + k * 32 + j]
                       : wk[(size_t)l * 8192 + k * 32 + (j - 32)];
    o[((size_t)l * 64 + j) * 256 + k] = f2b(v);
}

__global__ void k_bqk(const float* __restrict__ bq, const float* __restrict__ bk,
                      float* __restrict__ o) {
    const int l = blockIdx.x, j = threadIdx.x;
    o[l * 64 + j] = (j < 32) ? bq[l * 32 + j] : bk[l * 32 + (j - 32)];
}

__global__ __launch_bounds__(256) void k_cvt(const float* __restrict__ in,
                                             unsigned short* __restrict__ out) {
    int i = blockIdx.x * 256 + threadIdx.x;
    out[i] = f2b(in[i]);
}

// im2col: xpatch[tok][pi*16+pj] = bf16(x[b, gi*16+pi, gj*16+pj])
__global__ __launch_bounds__(256) void k_im2col(const float* __restrict__ x,
                                                unsigned short* __restrict__ xp) {
    const int tok = blockIdx.x;
    const int b  = tok >> 10;
    const int n  = tok & (NN - 1);
    const int gi = n >> 5, gj = n & 31;
    const int pi = threadIdx.x >> 4, pj = threadIdx.x & 15;
    xp[(size_t)tok * 256 + threadIdx.x] =
        f2b(x[(size_t)(b * IMG + gi * PP + pi) * IMG + gj * PP + pj]);
}

// ---------------- MFMA bf16 GEMM: C[M,N] = A[M,K] @ Bt[N,K]^T ----------------
// 64x64 tile, 256 threads (4 waves 2x2).
// MODE 0: Cb = bf16(gelu(acc+bias))     MODE 1: Cf += acc+bias
// MODE 2: Cb = bf16(acc+bias)           MODE 3: Cf += tanh(acc+bias)
// MODE 4: Cf  = acc+bias + pos[(m&1023)*N+n]
template <int K, int N, int MODE>
__global__ __launch_bounds__(256) void k_gemm(
    const unsigned short* __restrict__ A, const unsigned short* __restrict__ Bt,
    const float* __restrict__ bias, unsigned short* __restrict__ Cb,
    float* __restrict__ Cf, const float* __restrict__ pos) {
    __shared__ alignas(16) unsigned short As[64 * 32];
    __shared__ alignas(16) unsigned short Bs[64 * 32];
    const int t  = threadIdx.x;
    const int m0 = blockIdx.x * 64, n0 = blockIdx.y * 64;
    const int row = t >> 2, ch = t & 3;
    const unsigned short* ga = A  + (size_t)(m0 + row) * K + ch * 8;
    const unsigned short* gb = Bt + (size_t)(n0 + row) * K + ch * 8;

    const int lane = t & 63, wid = t >> 6;
    const int quad = lane >> 4, r = lane & 15;
    const int wm = (wid >> 1) * 32, wn = (wid & 1) * 32;

    floatx4 acc00 = {0.f, 0.f, 0.f, 0.f}, acc01 = {0.f, 0.f, 0.f, 0.f};
    floatx4 acc10 = {0.f, 0.f, 0.f, 0.f}, acc11 = {0.f, 0.f, 0.f, 0.f};

    uint4 ra = *(const uint4*)ga;
    uint4 rb = *(const uint4*)gb;
    const int KS = K / 32;
    for (int ks = 0; ks < KS; ++ks) {
        __syncthreads();
        *(uint4*)&As[t * 8] = ra;
        *(uint4*)&Bs[t * 8] = rb;
        __syncthreads();
        if (ks + 1 < KS) {
            ra = *(const uint4*)(ga + (ks + 1) * 32);
            rb = *(const uint4*)(gb + (ks + 1) * 32);
        }
        short8 a0 = *(const short8*)&As[(wm + r) * 32 + quad * 8];
        short8 a1 = *(const short8*)&As[(wm + 16 + r) * 32 + quad * 8];
        short8 b0 = *(const short8*)&Bs[(wn + r) * 32 + quad * 8];
        short8 b1 = *(const short8*)&Bs[(wn + 16 + r) * 32 + quad * 8];
        acc00 = __builtin_amdgcn_mfma_f32_16x16x32_bf16(a0, b0, acc00, 0, 0, 0);
        acc01 = __builtin_amdgcn_mfma_f32_16x16x32_bf16(a0, b1, acc01, 0, 0, 0);
        acc10 = __builtin_amdgcn_mfma_f32_16x16x32_bf16(a1, b0, acc10, 0, 0, 0);
        acc11 = __builtin_amdgcn_mfma_f32_16x16x32_bf16(a1, b1, acc11, 0, 0, 0);
    }
    const int nA = n0 + wn + r;
    const int nB = nA + 16;
    const float bias0 = bias[nA], bias1 = bias[nB];
    #pragma unroll
    for (int i = 0; i < 2; ++i) {
        floatx4 aj0 = i ? acc10 : acc00;
        floatx4 aj1 = i ? acc11 : acc01;
        const int mb = m0 + wm + i * 16 + quad * 4;
        #pragma unroll
        for (int g = 0; g < 4; ++g) {
            const int m = mb + g;
            float v0 = aj0[g] + bias0, v1 = aj1[g] + bias1;
            if (MODE == 0) {
                Cb[(size_t)m * N + nA] = f2b(gelu_exact(v0));
                Cb[(size_t)m * N + nB] = f2b(gelu_exact(v1));
            } else if (MODE == 1) {
                Cf[(size_t)m * N + nA] += v0;
                Cf[(size_t)m * N + nB] += v1;
            } else if (MODE == 2) {
                Cb[(size_t)m * N + nA] = f2b(v0);
                Cb[(size_t)m * N + nB] = f2b(v1);
            } else if (MODE == 3) {
                Cf[(size_t)m * N + nA] += tanhf(v0);
                Cf[(size_t)m * N + nB] += tanhf(v1);
            } else {
                Cf[(size_t)m * N + nA] = v0 + pos[(size_t)(m & (NN - 1)) * N + nA];
                Cf[(size_t)m * N + nB] = v1 + pos[(size_t)(m & (NN - 1)) * N + nB];
            }
        }
    }
}

// ---------------- depthwise Laplacian (SAME, zero pad) -> bf16 ----------------
__global__ __launch_bounds__(256) void k_lap(const float* __restrict__ h,
                                             unsigned short* __restrict__ e) {
    int idx = blockIdx.x * 256 + threadIdx.x;
    int n  = (idx >> 8) & (NN - 1);
    int gi = n >> 5, gj = n & 31;
    float c  = h[idx];
    float up = (gi > 0)  ? h[idx - GG * DD] : 0.f;
    float dn = (gi < 31) ? h[idx + GG * DD] : 0.f;
    float lf = (gj > 0)  ? h[idx - DD] : 0.f;
    float rt = (gj < 31) ? h[idx + DD] : 0.f;
    e[idx] = f2b(4.f * c - up - dn - lf - rt);
}

// ---------------- LayerNorm (wave per row) -> bf16 ----------------
__global__ __launch_bounds__(256) void k_ln(
    const float* __restrict__ h, const float* __restrict__ g,
    const float* __restrict__ b, unsigned short* __restrict__ xnb, int layer) {
    const int wid = threadIdx.x >> 6, lane = threadIdx.x & 63;
    const int row = blockIdx.x * 4 + wid;
    const float4 xv = *(const float4*)(h + (size_t)row * DD + lane * 4);
    float s = xv.x + xv.y + xv.z + xv.w;
    #pragma unroll
    for (int o = 32; o; o >>= 1) s += __shfl_xor(s, o, 64);
    const float m = s * (1.f / 256.f);
    float t0 = xv.x - m, t1 = xv.y - m, t2 = xv.z - m, t3 = xv.w - m;
    float s2 = t0 * t0 + t1 * t1 + t2 * t2 + t3 * t3;
    #pragma unroll
    for (int o = 32; o; o >>= 1) s2 += __shfl_xor(s2, o, 64);
    const float r = rsqrtf(s2 * (1.f / 256.f) + 1e-5f);
    const int d0 = lane * 4;
    const float4 gv = *(const float4*)(g + layer * DD + d0);
    const float4 bv = *(const float4*)(b + layer * DD + d0);
    unsigned short* o = xnb + (size_t)row * DD + d0;
    o[0] = f2b(t0 * r * gv.x + bv.x);
    o[1] = f2b(t1 * r * gv.y + bv.y);
    o[2] = f2b(t2 * r * gv.z + bv.z);
    o[3] = f2b(t3 * r * gv.w + bv.w);
}

// ---------------- criss-cross attention + residual ----------------
__global__ __launch_bounds__(256) void k_attn(
    const unsigned short* __restrict__ qkb, const unsigned short* __restrict__ v,
    const unsigned short* __restrict__ xnb, float* __restrict__ h,
    const float* __restrict__ gamma, int layer) {
    const int blk = blockIdx.x;            // b*1024 + gi*32 + gj
    const int b  = blk >> 10;
    const int gi = (blk >> 5) & 31;
    const int gj = blk & 31;
    const int tid = threadIdx.x;
    __shared__ float qs[32];
    __shared__ float as[64];
    if (tid < 32) qs[tid] = bu2f(qkb[(size_t)blk * 64 + tid]);
    __syncthreads();
    if (tid < 64) {
        int kidx;
        if (tid < 32) kidx = (b * GG + gi) * GG + tid;        // row
        else          kidx = (b * GG + (tid - 32)) * GG + gj; // col
        const unsigned short* kr = qkb + (size_t)kidx * 64 + 32;
        float s = 0.f;
        #pragma unroll
        for (int c = 0; c < 32; ++c) s += qs[c] * bu2f(kr[c]);
        s *= 0.17677669529663687f;
        if (tid >= 32 && (tid - 32) == gi) s -= 1e9f;
        float m = s;
        #pragma unroll
        for (int o = 32; o; o >>= 1) m = fmaxf(m, __shfl_xor(m, o, 64));
        float e = expf(s - m);
        float sum = e;
        #pragma unroll
        for (int o = 32; o; o >>= 1) sum += __shfl_xor(sum, o, 64);
        as[tid] = e / sum;
    }
    __syncthreads();
    const int d = tid;
    float out = 0.f;
    const unsigned short* vrow = v + ((size_t)(b * GG + gi) * GG) * DD + d;
    #pragma unroll 4
    for (int w = 0; w < 32; ++w) out += as[w] * bu2f(vrow[(size_t)w * DD]);
    const unsigned short* vcol = v + ((size_t)b * NN + gj) * DD + d;
    #pragma unroll 4
    for (int u = 0; u < 32; ++u) out += as[32 + u] * bu2f(vcol[(size_t)u * GG * DD]);
    size_t idx = (size_t)blk * DD + d;
    h[idx] += bu2f(xnb[idx]) + gamma[layer] * out;
}

// ---------------- head ----------------
__global__ __launch_bounds__(256) void k_head(
    const float* __restrict__ h, const float* __restrict__ wh,
    const float* __restrict__ bh, float* __restrict__ out) {
    const int tok  = blockIdx.x * 4 + (threadIdx.x >> 6);
    const int lane = threadIdx.x & 63;
    float acc = 0.f;
    #pragma unroll
    for (int i = 0; i < 4; ++i)
        acc += h[(size_t)tok * DD + lane + 64 * i] * wh[lane + 64 * i];
    #pragma unroll
    for (int o = 32; o; o >>= 1) acc += __shfl_down(acc, o, 64);
    if (lane == 0) out[tok] = acc + bh[0];
}

extern "C" void kernel_launch(void* const* d_in, const int* in_sizes, int n_in,
                              void* d_out, int out_size, void* d_ws, size_t ws_size,
                              hipStream_t stream) {
    const float* fx   = (const float*)d_in[0];
    const float* fwp  = (const float*)d_in[1];
    const float* fbp  = (const float*)d_in[2];
    const float* fpos = (const float*)d_in[3];
    const float* fwe  = (const float*)d_in[4];
    const float* fbe  = (const float*)d_in[5];
    const float* flg  = (const float*)d_in[6];
    const float* flb  = (const float*)d_in[7];
    const float* fwq  = (const float*)d_in[8];
    const float* fbq  = (const float*)d_in[9];
    const float* fwk  = (const float*)d_in[10];
    const float* fbk  = (const float*)d_in[11];
    const float* fwv  = (const float*)d_in[12];
    const float* fbv  = (const float*)d_in[13];
    const float* fgam = (const float*)d_in[14];
    const float* fw1  = (const float*)d_in[15];
    const float* fb1  = (const float*)d_in[16];
    const float* fw2  = (const float*)d_in[17];
    const float* fb2  = (const float*)d_in[18];
    const float* fwh  = (const float*)d_in[19];
    const float* fbh  = (const float*)d_in[20];
    float* out = (float*)d_out;

    // workspace layout (float offsets), total 20,316,672 f = 81.3 MB
    float* ws = (float*)d_ws;
    float*          h    = ws;                                   // 8,388,608 f
    unsigned short* xnb  = (unsigned short*)(ws + 8388608);      // 8,388,608 bf16
    unsigned short* w1t  = (unsigned short*)(ws + 12582912);     // 8x1024x256 bf16
    unsigned short* w2t  = (unsigned short*)(ws + 13631488);     // 8x256x1024 bf16
    unsigned short* wvT  = (unsigned short*)(ws + 14680064);     // 8x256x256 bf16
    unsigned short* wqkT = (unsigned short*)(ws + 14942208);     // 8x64x256 bf16
    unsigned short* wpb  = (unsigned short*)(ws + 15007744);     // 256x256 bf16
    unsigned short* weT  = (unsigned short*)(ws + 15040512);     // 256x256 bf16
    float*          bqk  = ws + 15073280;                        // 8x64 f
    // phase-disjoint scratch at S:
    float* S = ws + 15073792;
    unsigned short* qkb  = (unsigned short*)S;                   // 32768x64 bf16
    unsigned short* v    = (unsigned short*)(S + 1048576);       // 32768x256 bf16
    unsigned short* xp   = (unsigned short*)S;                   // pre-loop im2col
    unsigned short* e    = (unsigned short*)S;                   // pre-loop Laplacian
    unsigned short* Hc   = (unsigned short*)S;                   // 8192x1024 bf16 (MLP)

    const int TOK = BB * NN;               // 32768

    // one-time weight prep
    k_wtrans<<<dim3(8, 32, 8), 256, 0, stream>>>(fw1, w1t, 256, 1024);
    k_wtrans<<<dim3(32, 8, 8), 256, 0, stream>>>(fw2, w2t, 1024, 256);
    k_wtrans<<<dim3(8, 8, 8),  256, 0, stream>>>(fwv, wvT, 256, 256);
    k_wtrans<<<dim3(8, 8, 1),  256, 0, stream>>>(fwe, weT, 256, 256);
    k_qktrans<<<dim3(64, 1, 8), 256, 0, stream>>>(fwq, fwk, wqkT);
    k_bqk<<<8, 64, 0, stream>>>(fbq, fbk, bqk);
    k_cvt<<<256, 256, 0, stream>>>(fwp, wpb);

    // patch embed (GEMM) + pos
    k_im2col<<<TOK, 256, 0, stream>>>(fx, xp);
    k_gemm<256, 256, 4><<<dim3(512, 4), 256, 0, stream>>>(
        xp, wpb, fbp, nullptr, h, fpos);
    // edge tokens
    k_lap<<<TOK, 256, 0, stream>>>(h, e);
    k_gemm<256, 256, 3><<<dim3(512, 4), 256, 0, stream>>>(
        e, weT, fbe, nullptr, h, nullptr);

    for (int l = 0; l < DEPTH_; ++l) {
        k_ln<<<TOK / 4, 256, 0, stream>>>(h, flg, flb, xnb, l);
        k_gemm<256, 64, 2><<<dim3(512, 1), 256, 0, stream>>>(
            xnb, wqkT + (size_t)l * 16384, bqk + l * 64, qkb, nullptr, nullptr);
        k_gemm<256, 256, 2><<<dim3(512, 4), 256, 0, stream>>>(
            xnb, wvT + (size_t)l * 65536, fbv + l * 256, v, nullptr, nullptr);
        k_attn<<<TOK, 256, 0, stream>>>(qkb, v, xnb, h, fgam, l);
        k_ln<<<TOK / 4, 256, 0, stream>>>(h, flg, flb, xnb, l);
        for (int c = 0; c < 4; ++c) {
            k_gemm<256, 1024, 0><<<dim3(128, 16), 256, 0, stream>>>(
                xnb + (size_t)c * 8192 * 256, w1t + (size_t)l * 262144,
                fb1 + (size_t)l * 1024, Hc, nullptr, nullptr);
            k_gemm<1024, 256, 1><<<dim3(128, 4), 256, 0, stream>>>(
                Hc, w2t + (size_t)l * 262144,
                fb2 + (size_t)l * 256, nullptr, h + (size_t)c * 8192 * 256, nullptr);
        }
    }

    k_head<<<TOK / 4, 256, 0, stream>>>(h, fwh, fbh, out);
}

// Round 6
// 1853.788 us; speedup vs baseline: 8.3408x; 1.3031x over previous
//
#include <hip/hip_runtime.h>
#include <hip/hip_bf16.h>

#define BB   32
#define IMG  512
#define PP   16
#define DD   256
#define GG   32
#define NN   1024
#define DQ_  32
#define DF_  1024
#define DEPTH_ 8

using short8  = __attribute__((ext_vector_type(8))) short;
using floatx4 = __attribute__((ext_vector_type(4))) float;

__device__ __forceinline__ float bu2f(unsigned short u) {
    return __uint_as_float(((unsigned int)u) << 16);
}
__device__ __forceinline__ unsigned short f2b(float f) {   // round-to-nearest-even
    unsigned int u = __float_as_uint(f);
    u += 0x7fffu + ((u >> 16) & 1u);
    return (unsigned short)(u >> 16);
}
__device__ __forceinline__ float gelu_exact(float x) {
    return 0.5f * x * (1.0f + erff(x * 0.70710678118654752440f));
}
__device__ __forceinline__ float lo16(unsigned int u) {
    return __uint_as_float(u << 16);
}
__device__ __forceinline__ float hi16(unsigned int u) {
    return __uint_as_float(u & 0xffff0000u);
}
__device__ __forceinline__ float dot8(uint4 a, uint4 b) {
    const unsigned int* pa = (const unsigned int*)&a;
    const unsigned int* pb = (const unsigned int*)&b;
    float s = 0.f;
    #pragma unroll
    for (int i = 0; i < 4; ++i)
        s += lo16(pa[i]) * lo16(pb[i]) + hi16(pa[i]) * hi16(pb[i]);
    return s;
}

// ---------------- weight transpose+convert: [L][R][C] f32 -> [L][C][R] bf16 ----------------
__global__ __launch_bounds__(256) void k_wtrans(const float* __restrict__ in,
                                                unsigned short* __restrict__ out,
                                                int R, int C) {
    __shared__ float tile[32][33];
    const int l = blockIdx.z;
    const int r0 = blockIdx.x * 32, c0 = blockIdx.y * 32;
    const int tx = threadIdx.x & 31, ty = threadIdx.x >> 5;
    const float* src = in + (size_t)l * R * C;
    unsigned short* dst = out + (size_t)l * R * C;
    #pragma unroll
    for (int i = 0; i < 4; ++i)
        tile[ty + i * 8][tx] = src[(size_t)(r0 + ty + i * 8) * C + c0 + tx];
    __syncthreads();
    #pragma unroll
    for (int i = 0; i < 4; ++i)
        dst[(size_t)(c0 + ty + i * 8) * R + r0 + tx] = f2b(tile[tx][ty + i * 8]);
}

// stacked qk transpose: wqkT[l][j][k] = j<32 ? wq[l][k][j] : wk[l][k][j-32]
__global__ __launch_bounds__(256) void k_qktrans(const float* __restrict__ wq,
                                                 const float* __restrict__ wk,
                                                 unsigned short* __restrict__ o) {
    const int l = blockIdx.z, j = blockIdx.x, k = threadIdx.x;
    float v = (j < 32) ? wq[(size_t)l * 8192 + k * 32 + j]
                       : wk[(size_t)l * 8192 + k * 32 + (j - 32)];
    o[((size_t)l * 64 + j) * 256 + k] = f2b(v);
}

__global__ void k_bqk(const float* __restrict__ bq, const float* __restrict__ bk,
                      float* __restrict__ o) {
    const int l = blockIdx.x, j = threadIdx.x;
    o[l * 64 + j] = (j < 32) ? bq[l * 32 + j] : bk[l * 32 + (j - 32)];
}

__global__ __launch_bounds__(256) void k_cvt(const float* __restrict__ in,
                                             unsigned short* __restrict__ out) {
    int i = blockIdx.x * 256 + threadIdx.x;
    out[i] = f2b(in[i]);
}

// im2col
__global__ __launch_bounds__(256) void k_im2col(const float* __restrict__ x,
                                                unsigned short* __restrict__ xp) {
    const int tok = blockIdx.x;
    const int b  = tok >> 10;
    const int n  = tok & (NN - 1);
    const int gi = n >> 5, gj = n & 31;
    const int pi = threadIdx.x >> 4, pj = threadIdx.x & 15;
    xp[(size_t)tok * 256 + threadIdx.x] =
        f2b(x[(size_t)(b * IMG + gi * PP + pi) * IMG + gj * PP + pj]);
}

// ---------------- MFMA bf16 GEMM: C[M,N] = A[M,K] @ Bt[N,K]^T ----------------
// MODE 0: Cb=bf16(gelu(acc+bias))  1: Cf+=acc+bias  2: Cb=bf16(acc+bias)
// MODE 3: Cf+=tanh(acc+bias)       4: Cf=acc+bias+pos
template <int K, int N, int MODE>
__global__ __launch_bounds__(256) void k_gemm(
    const unsigned short* __restrict__ A, const unsigned short* __restrict__ Bt,
    const float* __restrict__ bias, unsigned short* __restrict__ Cb,
    float* __restrict__ Cf, const float* __restrict__ pos) {
    __shared__ alignas(16) unsigned short As[64 * 32];
    __shared__ alignas(16) unsigned short Bs[64 * 32];
    const int t  = threadIdx.x;
    const int m0 = blockIdx.x * 64, n0 = blockIdx.y * 64;
    const int row = t >> 2, ch = t & 3;
    const unsigned short* ga = A  + (size_t)(m0 + row) * K + ch * 8;
    const unsigned short* gb = Bt + (size_t)(n0 + row) * K + ch * 8;

    const int lane = t & 63, wid = t >> 6;
    const int quad = lane >> 4, r = lane & 15;
    const int wm = (wid >> 1) * 32, wn = (wid & 1) * 32;

    floatx4 acc00 = {0.f, 0.f, 0.f, 0.f}, acc01 = {0.f, 0.f, 0.f, 0.f};
    floatx4 acc10 = {0.f, 0.f, 0.f, 0.f}, acc11 = {0.f, 0.f, 0.f, 0.f};

    uint4 ra = *(const uint4*)ga;
    uint4 rb = *(const uint4*)gb;
    const int KS = K / 32;
    for (int ks = 0; ks < KS; ++ks) {
        __syncthreads();
        *(uint4*)&As[t * 8] = ra;
        *(uint4*)&Bs[t * 8] = rb;
        __syncthreads();
        if (ks + 1 < KS) {
            ra = *(const uint4*)(ga + (ks + 1) * 32);
            rb = *(const uint4*)(gb + (ks + 1) * 32);
        }
        short8 a0 = *(const short8*)&As[(wm + r) * 32 + quad * 8];
        short8 a1 = *(const short8*)&As[(wm + 16 + r) * 32 + quad * 8];
        short8 b0 = *(const short8*)&Bs[(wn + r) * 32 + quad * 8];
        short8 b1 = *(const short8*)&Bs[(wn + 16 + r) * 32 + quad * 8];
        acc00 = __builtin_amdgcn_mfma_f32_16x16x32_bf16(a0, b0, acc00, 0, 0, 0);
        acc01 = __builtin_amdgcn_mfma_f32_16x16x32_bf16(a0, b1, acc01, 0, 0, 0);
        acc10 = __builtin_amdgcn_mfma_f32_16x16x32_bf16(a1, b0, acc10, 0, 0, 0);
        acc11 = __builtin_amdgcn_mfma_f32_16x16x32_bf16(a1, b1, acc11, 0, 0, 0);
    }
    const int nA = n0 + wn + r;
    const int nB = nA + 16;
    const float bias0 = bias[nA], bias1 = bias[nB];
    #pragma unroll
    for (int i = 0; i < 2; ++i) {
        floatx4 aj0 = i ? acc10 : acc00;
        floatx4 aj1 = i ? acc11 : acc01;
        const int mb = m0 + wm + i * 16 + quad * 4;
        #pragma unroll
        for (int g = 0; g < 4; ++g) {
            const int m = mb + g;
            float v0 = aj0[g] + bias0, v1 = aj1[g] + bias1;
            if (MODE == 0) {
                Cb[(size_t)m * N + nA] = f2b(gelu_exact(v0));
                Cb[(size_t)m * N + nB] = f2b(gelu_exact(v1));
            } else if (MODE == 1) {
                Cf[(size_t)m * N + nA] += v0;
                Cf[(size_t)m * N + nB] += v1;
            } else if (MODE == 2) {
                Cb[(size_t)m * N + nA] = f2b(v0);
                Cb[(size_t)m * N + nB] = f2b(v1);
            } else if (MODE == 3) {
                Cf[(size_t)m * N + nA] += tanhf(v0);
                Cf[(size_t)m * N + nB] += tanhf(v1);
            } else {
                Cf[(size_t)m * N + nA] = v0 + pos[(size_t)(m & (NN - 1)) * N + nA];
                Cf[(size_t)m * N + nB] = v1 + pos[(size_t)(m & (NN - 1)) * N + nB];
            }
        }
    }
}

// ---------------- depthwise Laplacian (SAME, zero pad) -> bf16 ----------------
__global__ __launch_bounds__(256) void k_lap(const float* __restrict__ h,
                                             unsigned short* __restrict__ e) {
    int idx = blockIdx.x * 256 + threadIdx.x;
    int n  = (idx >> 8) & (NN - 1);
    int gi = n >> 5, gj = n & 31;
    float c  = h[idx];
    float up = (gi > 0)  ? h[idx - GG * DD] : 0.f;
    float dn = (gi < 31) ? h[idx + GG * DD] : 0.f;
    float lf = (gj > 0)  ? h[idx - DD] : 0.f;
    float rt = (gj < 31) ? h[idx + DD] : 0.f;
    e[idx] = f2b(4.f * c - up - dn - lf - rt);
}

// ---------------- LayerNorm (wave per row) -> bf16 ----------------
__global__ __launch_bounds__(256) void k_ln(
    const float* __restrict__ h, const float* __restrict__ g,
    const float* __restrict__ b, unsigned short* __restrict__ xnb, int layer) {
    const int wid = threadIdx.x >> 6, lane = threadIdx.x & 63;
    const int row = blockIdx.x * 4 + wid;
    const float4 xv = *(const float4*)(h + (size_t)row * DD + lane * 4);
    float s = xv.x + xv.y + xv.z + xv.w;
    #pragma unroll
    for (int o = 32; o; o >>= 1) s += __shfl_xor(s, o, 64);
    const float m = s * (1.f / 256.f);
    float t0 = xv.x - m, t1 = xv.y - m, t2 = xv.z - m, t3 = xv.w - m;
    float s2 = t0 * t0 + t1 * t1 + t2 * t2 + t3 * t3;
    #pragma unroll
    for (int o = 32; o; o >>= 1) s2 += __shfl_xor(s2, o, 64);
    const float r = rsqrtf(s2 * (1.f / 256.f) + 1e-5f);
    const int d0 = lane * 4;
    const float4 gv = *(const float4*)(g + layer * DD + d0);
    const float4 bv = *(const float4*)(b + layer * DD + d0);
    unsigned short* o = xnb + (size_t)row * DD + d0;
    o[0] = f2b(t0 * r * gv.x + bv.x);
    o[1] = f2b(t1 * r * gv.y + bv.y);
    o[2] = f2b(t2 * r * gv.z + bv.z);
    o[3] = f2b(t3 * r * gv.w + bv.w);
}

// ---------------- attention scores + softmax -> P[tok][64] bf16 ----------------
// wave per token; lane = key index (0..31 row, 32..63 col)
__global__ __launch_bounds__(256) void k_score(
    const unsigned short* __restrict__ qkb, unsigned short* __restrict__ P) {
    const int wid = threadIdx.x >> 6, lane = threadIdx.x & 63;
    const int tok = blockIdx.x * 4 + wid;
    const int b = tok >> 10, n = tok & (NN - 1);
    const int gi = n >> 5, gj = n & 31;
    const uint4* qp = (const uint4*)(qkb + (size_t)tok * 64);
    uint4 q0 = qp[0], q1 = qp[1], q2 = qp[2], q3 = qp[3];
    const int key = (lane < 32) ? (b * NN + gi * 32 + lane)
                                : (b * NN + (lane - 32) * 32 + gj);
    const uint4* kp = (const uint4*)(qkb + (size_t)key * 64 + 32);
    uint4 k0 = kp[0], k1 = kp[1], k2 = kp[2], k3 = kp[3];
    float s = dot8(q0, k0) + dot8(q1, k1) + dot8(q2, k2) + dot8(q3, k3);
    s *= 0.17677669529663687f;                // 1/sqrt(32)
    if (lane >= 32 && (lane - 32) == gi) s -= 1e9f;
    float m = s;
    #pragma unroll
    for (int o = 32; o; o >>= 1) m = fmaxf(m, __shfl_xor(m, o, 64));
    float e = expf(s - m);
    float sum = e;
    #pragma unroll
    for (int o = 32; o; o >>= 1) sum += __shfl_xor(sum, o, 64);
    P[(size_t)tok * 64 + lane] = f2b(e / sum);
}

// ---------------- row A*V + residual: h += xn + gamma*out_row ----------------
// block per (b,gi); wave handles 8 gj tokens; lane covers d = lane*4..+3
__global__ __launch_bounds__(256) void k_avrow(
    const unsigned short* __restrict__ P, const unsigned short* __restrict__ v,
    const unsigned short* __restrict__ xnb, float* __restrict__ h,
    const float* __restrict__ gamma, int layer) {
    const int bgi = blockIdx.x;
    const int wid = threadIdx.x >> 6, lane = threadIdx.x & 63;
    const int d0 = lane * 4;
    uint2 vr[32];
    const unsigned short* vbase = v + ((size_t)bgi * 32) * 256 + d0;
    #pragma unroll
    for (int w = 0; w < 32; ++w) vr[w] = *(const uint2*)(vbase + (size_t)w * 256);
    const float g = gamma[layer];
    for (int j = 0; j < 8; ++j) {
        const int tok = bgi * 32 + wid * 8 + j;
        const uint4* pp = (const uint4*)(P + (size_t)tok * 64);
        unsigned int pa[16];
        *(uint4*)(pa)      = pp[0];
        *(uint4*)(pa + 4)  = pp[1];
        *(uint4*)(pa + 8)  = pp[2];
        *(uint4*)(pa + 12) = pp[3];
        float o0 = 0.f, o1 = 0.f, o2 = 0.f, o3 = 0.f;
        #pragma unroll
        for (int w = 0; w < 32; ++w) {
            float p = (w & 1) ? hi16(pa[w >> 1]) : lo16(pa[w >> 1]);
            o0 += p * lo16(vr[w].x); o1 += p * hi16(vr[w].x);
            o2 += p * lo16(vr[w].y); o3 += p * hi16(vr[w].y);
        }
        size_t idx = (size_t)tok * 256 + d0;
        uint2 xu = *(const uint2*)(xnb + idx);
        float4 hv = *(float4*)(h + idx);
        hv.x += lo16(xu.x) + g * o0; hv.y += hi16(xu.x) + g * o1;
        hv.z += lo16(xu.y) + g * o2; hv.w += hi16(xu.y) + g * o3;
        *(float4*)(h + idx) = hv;
    }
}

// ---------------- col A*V: h += gamma*out_col ----------------
__global__ __launch_bounds__(256) void k_avcol(
    const unsigned short* __restrict__ P, const unsigned short* __restrict__ v,
    float* __restrict__ h, const float* __restrict__ gamma, int layer) {
    const int bgj = blockIdx.x;
    const int b = bgj >> 5, gj = bgj & 31;
    const int wid = threadIdx.x >> 6, lane = threadIdx.x & 63;
    const int d0 = lane * 4;
    uint2 vr[32];
    const unsigned short* vbase = v + ((size_t)b * NN + gj) * 256 + d0;
    #pragma unroll
    for (int u = 0; u < 32; ++u)
        vr[u] = *(const uint2*)(vbase + (size_t)u * 32 * 256);
    const float g = gamma[layer];
    for (int j = 0; j < 8; ++j) {
        const int gi = wid * 8 + j;
        const int tok = (b * 32 + gi) * 32 + gj;
        const uint4* pp = (const uint4*)(P + (size_t)tok * 64 + 32);
        unsigned int pa[16];
        *(uint4*)(pa)      = pp[0];
        *(uint4*)(pa + 4)  = pp[1];
        *(uint4*)(pa + 8)  = pp[2];
        *(uint4*)(pa + 12) = pp[3];
        float o0 = 0.f, o1 = 0.f, o2 = 0.f, o3 = 0.f;
        #pragma unroll
        for (int u = 0; u < 32; ++u) {
            float p = (u & 1) ? hi16(pa[u >> 1]) : lo16(pa[u >> 1]);
            o0 += p * lo16(vr[u].x); o1 += p * hi16(vr[u].x);
            o2 += p * lo16(vr[u].y); o3 += p * hi16(vr[u].y);
        }
        size_t idx = (size_t)tok * 256 + d0;
        float4 hv = *(float4*)(h + idx);
        hv.x += g * o0; hv.y += g * o1; hv.z += g * o2; hv.w += g * o3;
        *(float4*)(h + idx) = hv;
    }
}

// ---------------- head ----------------
__global__ __launch_bounds__(256) void k_head(
    const float* __restrict__ h, const float* __restrict__ wh,
    const float* __restrict__ bh, float* __restrict__ out) {
    const int tok  = blockIdx.x * 4 + (threadIdx.x >> 6);
    const int lane = threadIdx.x & 63;
    float acc = 0.f;
    #pragma unroll
    for (int i = 0; i < 4; ++i)
        acc += h[(size_t)tok * DD + lane + 64 * i] * wh[lane + 64 * i];
    #pragma unroll
    for (int o = 32; o; o >>= 1) acc += __shfl_down(acc, o, 64);
    if (lane == 0) out[tok] = acc + bh[0];
}

extern "C" void kernel_launch(void* const* d_in, const int* in_sizes, int n_in,
                              void* d_out, int out_size, void* d_ws, size_t ws_size,
                              hipStream_t stream) {
    const float* fx   = (const float*)d_in[0];
    const float* fwp  = (const float*)d_in[1];
    const float* fbp  = (const float*)d_in[2];
    const float* fpos = (const float*)d_in[3];
    const float* fwe  = (const float*)d_in[4];
    const float* fbe  = (const float*)d_in[5];
    const float* flg  = (const float*)d_in[6];
    const float* flb  = (const float*)d_in[7];
    const float* fwq  = (const float*)d_in[8];
    const float* fbq  = (const float*)d_in[9];
    const float* fwk  = (const float*)d_in[10];
    const float* fbk  = (const float*)d_in[11];
    const float* fwv  = (const float*)d_in[12];
    const float* fbv  = (const float*)d_in[13];
    const float* fgam = (const float*)d_in[14];
    const float* fw1  = (const float*)d_in[15];
    const float* fb1  = (const float*)d_in[16];
    const float* fw2  = (const float*)d_in[17];
    const float* fb2  = (const float*)d_in[18];
    const float* fwh  = (const float*)d_in[19];
    const float* fbh  = (const float*)d_in[20];
    float* out = (float*)d_out;

    // workspace (float offsets); high-water 93.8 MB (R3 proved ws >= 109 MB)
    float* ws = (float*)d_ws;
    float*          h    = ws;                                   // 8,388,608 f
    unsigned short* xnb  = (unsigned short*)(ws + 8388608);      // 32768x256 bf16
    unsigned short* w1t  = (unsigned short*)(ws + 12582912);
    unsigned short* w2t  = (unsigned short*)(ws + 13631488);
    unsigned short* wvT  = (unsigned short*)(ws + 14680064);
    unsigned short* wqkT = (unsigned short*)(ws + 14942208);
    unsigned short* wpb  = (unsigned short*)(ws + 15007744);
    unsigned short* weT  = (unsigned short*)(ws + 15040512);
    float*          bqk  = ws + 15073280;
    float* S = ws + 15073792;
    unsigned short* qkb  = (unsigned short*)S;                   // 32768x64 bf16
    unsigned short* v    = (unsigned short*)(S + 1048576);       // 32768x256 bf16
    unsigned short* P    = (unsigned short*)(S + 5242880);       // 32768x64 bf16
    unsigned short* xp   = (unsigned short*)S;                   // pre-loop
    unsigned short* e    = (unsigned short*)S;                   // pre-loop
    unsigned short* Hc   = (unsigned short*)S;                   // 16384x1024 bf16 (MLP)

    const int TOK = BB * NN;               // 32768

    // one-time weight prep
    k_wtrans<<<dim3(8, 32, 8), 256, 0, stream>>>(fw1, w1t, 256, 1024);
    k_wtrans<<<dim3(32, 8, 8), 256, 0, stream>>>(fw2, w2t, 1024, 256);
    k_wtrans<<<dim3(8, 8, 8),  256, 0, stream>>>(fwv, wvT, 256, 256);
    k_wtrans<<<dim3(8, 8, 1),  256, 0, stream>>>(fwe, weT, 256, 256);
    k_qktrans<<<dim3(64, 1, 8), 256, 0, stream>>>(fwq, fwk, wqkT);
    k_bqk<<<8, 64, 0, stream>>>(fbq, fbk, bqk);
    k_cvt<<<256, 256, 0, stream>>>(fwp, wpb);

    // patch embed (GEMM) + pos
    k_im2col<<<TOK, 256, 0, stream>>>(fx, xp);
    k_gemm<256, 256, 4><<<dim3(512, 4), 256, 0, stream>>>(
        xp, wpb, fbp, nullptr, h, fpos);
    // edge tokens
    k_lap<<<TOK, 256, 0, stream>>>(h, e);
    k_gemm<256, 256, 3><<<dim3(512, 4), 256, 0, stream>>>(
        e, weT, fbe, nullptr, h, nullptr);

    for (int l = 0; l < DEPTH_; ++l) {
        k_ln<<<TOK / 4, 256, 0, stream>>>(h, flg, flb, xnb, l);
        k_gemm<256, 64, 2><<<dim3(512, 1), 256, 0, stream>>>(
            xnb, wqkT + (size_t)l * 16384, bqk + l * 64, qkb, nullptr, nullptr);
        k_gemm<256, 256, 2><<<dim3(512, 4), 256, 0, stream>>>(
            xnb, wvT + (size_t)l * 65536, fbv + l * 256, v, nullptr, nullptr);
        k_score<<<TOK / 4, 256, 0, stream>>>(qkb, P);
        k_avcol<<<BB * GG, 256, 0, stream>>>(P, v, h, fgam, l);
        k_avrow<<<BB * GG, 256, 0, stream>>>(P, v, xnb, h, fgam, l);
        k_ln<<<TOK / 4, 256, 0, stream>>>(h, flg, flb, xnb, l);
        for (int c = 0; c < 2; ++c) {
            k_gemm<256, 1024, 0><<<dim3(256, 16), 256, 0, stream>>>(
                xnb + (size_t)c * 16384 * 256, w1t + (size_t)l * 262144,
                fb1 + (size_t)l * 1024, Hc, nullptr, nullptr);
            k_gemm<1024, 256, 1><<<dim3(256, 4), 256, 0, stream>>>(
                Hc, w2t + (size_t)l * 262144,
                fb2 + (size_t)l * 256, nullptr, h + (size_t)c * 16384 * 256, nullptr);
        }
    }

    k_head<<<TOK / 4, 256, 0, stream>>>(h, fwh, fbh, out);
}